// Round 23
// baseline (136.426 us; speedup 1.0000x reference)
//
#include <hip/hip_runtime.h>
#include <hip/hip_bf16.h>
#include <stdint.h>

typedef unsigned short u16;
typedef unsigned int u32;
typedef __attribute__((ext_vector_type(8))) short short8;
typedef __attribute__((ext_vector_type(4))) float f32x4;
typedef __attribute__((ext_vector_type(4))) unsigned int u32x4;
typedef __attribute__((ext_vector_type(4))) unsigned short u16x4;

#define MFMA16(a, b, c) __builtin_amdgcn_mfma_f32_16x16x32_bf16((a), (b), (c), 0, 0, 0)

__device__ __forceinline__ u16 f2bf(float f) {
    union { float f; uint32_t u; } v; v.f = f;
    return (u16)((v.u + 0x7FFFu + ((v.u >> 16) & 1u)) >> 16);
}
__device__ __forceinline__ u16 f2bf_up(float f) {  // round-half-up, f >= 0
    union { float f; uint32_t u; } v; v.f = f;
    return (u16)((v.u + 0x8000u) >> 16);
}

// async global -> LDS, 16 bytes per lane (dest must be linear: base + lane*16)
__device__ __forceinline__ void gl_lds16(const u16* g, u16* l) {
    __builtin_amdgcn_global_load_lds(
        (const __attribute__((address_space(1))) u32*)g,
        (__attribute__((address_space(3))) u32*)l,
        16, 0, 0);
}

// ---------------- merged convert kernel (one launch) ----------------

__global__ __launch_bounds__(256) void k_cvt(const float* __restrict__ x,
                                             const float* __restrict__ wq,
                                             const float* __restrict__ wp,
                                             u16* __restrict__ xb,
                                             u16* __restrict__ outq,
                                             u16* __restrict__ outp) {
    __shared__ u16 t[64][72];
    if (blockIdx.x < 3072) {
        int i = (blockIdx.x * 256 + threadIdx.x) * 8;
        f32x4 v0 = *(const f32x4*)(x + i);
        f32x4 v1 = *(const f32x4*)(x + i + 4);
        u16x4 o0, o1;
#pragma unroll
        for (int q = 0; q < 4; ++q) { o0[q] = f2bf(v0[q]); o1[q] = f2bf(v1[q]); }
        *(u16x4*)(xb + i) = o0;
        *(u16x4*)(xb + i + 4) = o1;
        return;
    }
    int bid = blockIdx.x - 3072;          // 0..575
    int bx = bid % 48, kb = (bid / 48) * 64;
    const float* in; u16* out; int N, nb;
    if (bx < 36) { in = wq; out = outq; N = 2304; nb = bx * 64; }
    else         { in = wp; out = outp; N = 768;  nb = (bx - 36) * 64; }
    const int tid = threadIdx.x;
    const int r = tid >> 4, c4 = (tid & 15) << 2;
#pragma unroll
    for (int p = 0; p < 4; ++p) {
        int k = r + p * 16;
        f32x4 v = *(const f32x4*)&in[(size_t)(kb + k) * N + nb + c4];
#pragma unroll
        for (int q = 0; q < 4; ++q) t[c4 + q][k] = f2bf(v[q]);
    }
    __syncthreads();
#pragma unroll
    for (int p = 0; p < 4; ++p) {
        int nn = r + p * 16;
        u16x4 o;
#pragma unroll
        for (int q = 0; q < 4; ++q) o[q] = t[nn][c4 + q];
        *(u16x4*)&out[(size_t)(nb + nn) * 768 + kb + c4] = o;
    }
}

// ---------------- GEMM1: persistent-lite 64x128 tiles, grid 768 (r21/r22 proven) ----------------

__global__ __launch_bounds__(256, 3) void k_gemm_qkv(const u16* __restrict__ A,
                                                     const u16* __restrict__ BT,
                                                     const float* __restrict__ bias,
                                                     u16* __restrict__ qkv,
                                                     u16* __restrict__ Vtg) {
    __shared__ __align__(16) u16 lds[2 * 12288];
    const int tid = threadIdx.x;
    int id = blockIdx.x;                        // 768 blocks
    int local = id >> 3, xcd = id & 7;
    int bxg = local >> 4;                       // 0..5
    int by = (xcd << 4) | (local & 15);         // XCD-private 16-row slab
    const int m0 = by * 64;

    const u16* Asrc = A + (size_t)m0 * 768;

    const int lane = tid & 63, wave = tid >> 6;
    const int wr = wave >> 1, wc = wave & 1;
    const int g = lane >> 4, lr = lane & 15;

    int ca[2], ra[2], ua[2], cb[4], rb[4], ub[4];
#pragma unroll
    for (int it = 0; it < 2; ++it) {
        int c = tid + it * 256;
        ca[it] = c; ra[it] = c >> 3; ua[it] = (c & 7) ^ (ra[it] & 7);
    }
#pragma unroll
    for (int it = 0; it < 4; ++it) {
        int c = tid + it * 256;
        cb[it] = c; rb[it] = c >> 3; ub[it] = (c & 7) ^ (rb[it] & 7);
    }

#define STAGE_AB(K0, DST, BSRC) do {                                          \
    u16* dA_ = (DST);                                                         \
    u16* dB_ = (DST) + 4096;                                                  \
    _Pragma("unroll") for (int it = 0; it < 2; ++it)                          \
        gl_lds16(&Asrc[(size_t)ra[it] * 768 + (K0) + ua[it] * 8],             \
                 &dA_[ca[it] * 8]);                                           \
    _Pragma("unroll") for (int it = 0; it < 4; ++it)                          \
        gl_lds16(&(BSRC)[(size_t)rb[it] * 768 + (K0) + ub[it] * 8],           \
                 &dB_[cb[it] * 8]);                                           \
} while (0)

    const float CS = 0.14724449f; // 1/sqrt(96) * log2(e)

    {
        const u16* B0 = BT + (size_t)(bxg * 3) * 128 * 768;
        STAGE_AB(0, lds, B0);
    }
    __syncthreads();

    for (int tile = 0; tile < 3; ++tile) {
        const int bx = bxg * 3 + tile;
        const int n0 = bx * 128;
        const u16* Bcur = BT + (size_t)n0 * 768;

        f32x4 acc[2][4];
#pragma unroll
        for (int i = 0; i < 2; ++i)
#pragma unroll
            for (int j = 0; j < 4; ++j) acc[i][j] = (f32x4){0.f, 0.f, 0.f, 0.f};

        for (int t = 0; t < 12; ++t) {
            const int cur = t & 1;
            if (t < 11) {
                STAGE_AB((t + 1) * 64, &lds[(cur ^ 1) * 12288], Bcur);
            } else if (tile < 2) {
                STAGE_AB(0, &lds[(cur ^ 1) * 12288], Bcur + 98304);
            }
            const u16* As = &lds[cur * 12288];
            const u16* Bs = As + 4096;
#pragma unroll
            for (int kk = 0; kk < 2; ++kk) {
                const int slot = ((4 * kk + g) ^ (lr & 7)) << 3;
                short8 af[2], bfv[4];
#pragma unroll
                for (int i = 0; i < 2; ++i)
                    af[i] = *(const short8*)&As[(32 * wr + 16 * i + lr) * 64 + slot];
#pragma unroll
                for (int j = 0; j < 4; ++j)
                    bfv[j] = *(const short8*)&Bs[(64 * wc + 16 * j + lr) * 64 + slot];
#pragma unroll
                for (int i = 0; i < 2; ++i)
#pragma unroll
                    for (int j = 0; j < 4; ++j)
                        acc[i][j] = MFMA16(af[i], bfv[j], acc[i][j]);
            }
            if (t < 11) __syncthreads();
        }

#pragma unroll
        for (int i = 0; i < 2; ++i) {
            int row = m0 + 32 * wr + 16 * i + 4 * g;
#pragma unroll
            for (int j = 0; j < 4; ++j) {
                int col = n0 + 64 * wc + 16 * j + lr;
                float bsv = bias[col];
                if (col < 1536) {
                    float sc = (col < 768) ? CS : 1.0f;
#pragma unroll
                    for (int r = 0; r < 4; ++r)
                        qkv[(size_t)(row + r) * 2304 + col] = f2bf((acc[i][j][r] + bsv) * sc);
                } else {
                    int jj = col - 1536;
                    int h = jj / 96, d = jj - h * 96;
                    int t2 = row & 1023, bb = row >> 10;
                    int bh = bb * 8 + h;
                    u16x4 vv;
#pragma unroll
                    for (int r = 0; r < 4; ++r) vv[r] = f2bf(acc[i][j][r] + bsv);
                    *(u16x4*)&Vtg[((size_t)bh * 96 + d) * 1024 + t2] = vv;
                }
            }
        }
        if (tile < 2) __syncthreads();
    }
#undef STAGE_AB
}

// ---------------- flash attention: INTERLEAVED segments (shared K/V staging) ----------------
// Each block handles q-tiles A (qtA=15-z) and B (qtB=z) CONCURRENTLY in one kt loop:
// both consume the same staged K/V tile; seg B active while kt <= qtB. Staged tiles
// 17 -> 16-z (avg 12.25); barriers likewise. K dbuf staged 2-ahead (write Ks[cur] after
// PV); V dbuf staged 1-ahead (write Vt[cur^1] after PV); all one-barrier-separated (r13).
// Adjacent blocks get complementary z (phase sums constant 25).
// LDS: K 32KB + V 24KB + Ps 2 segs x 4 waves x 2.25KB = 75776 B -> 2 blocks/CU.

__global__ __launch_bounds__(256) void k_attn(u16* __restrict__ qkv,
                                              const u16* __restrict__ Vtg) {
    __shared__ __align__(16) u16 sm[16384 + 12288 + 9216];
    u16* KsB = sm;                      // [2][64*128]
    u16* VtB = sm + 16384;              // [2][96*64]
    const int tid = threadIdx.x;
    const int wave = tid >> 6, lane = tid & 63;
    const int g = lane >> 4, lr = lane & 15;
    u16* PsA = sm + 16384 + 12288 + wave * 2304;  // [16][72]
    u16* PsB = PsA + 1152;                        // [16][72]

    int id = blockIdx.y * 8 + blockIdx.x;
    int xcd = id & 7, s = id >> 3;                // s: 0..63 per xcd
    int t_ = s >> 1;
    int bh = xcd * 8 + (t_ >> 2);
    int pz = t_ & 3;
    int z = (s & 1) ? 7 - pz : pz;                // adjacent blocks: z, 7-z
    const int b = bh >> 3, h = bh & 7;

    const int qtA = 15 - z, qtB = z;              // qtA >= 8 > 0 always

    const size_t rowb = (size_t)b * 1024;
    const int qcol = h * 96;
    const int kcol = 768 + h * 96;
    const size_t vbase = (size_t)bh * 96 * 1024;

    int kld[3], vld[3];
    size_t kgo[3], vgo[3];
#pragma unroll
    for (int it = 0; it < 3; ++it) {
        int c = tid + it * 256;
        int r = c / 12, ss = c - r * 12;
        kgo[it] = (size_t)r * 2304 + kcol + ss * 8;
        kld[it] = r * 128 + ((ss ^ (r & 7)) << 3);
        int vr = c >> 3, vs = c & 7;
        vgo[it] = (size_t)vr * 1024 + vs * 8;
        vld[it] = vr * 64 + ((vs ^ (vr & 7)) << 3);
    }

    const short8 onesf = (short8){0x3F80, 0x3F80, 0x3F80, 0x3F80,
                                  0x3F80, 0x3F80, 0x3F80, 0x3F80};

    // Q fragments for both segments
    short8 qfA[3], qfB[3];
    {
        int qrA = qtA * 64 + 16 * wave + lr;
        int qrB = qtB * 64 + 16 * wave + lr;
#pragma unroll
        for (int kk = 0; kk < 3; ++kk) {
            qfA[kk] = *(const short8*)&qkv[(rowb + qrA) * 2304 + qcol + 32 * kk + 8 * g];
            qfB[kk] = *(const short8*)&qkv[(rowb + qrB) * 2304 + qcol + 32 * kk + 8 * g];
        }
    }

    float mA[4], mB[4];
    f32x4 oA[7], oB[7];
#pragma unroll
    for (int r = 0; r < 4; ++r) { mA[r] = -3e38f; mB[r] = -3e38f; }
#pragma unroll
    for (int c = 0; c < 7; ++c) {
        oA[c] = (f32x4){0.f, 0.f, 0.f, 0.f};
        oB[c] = (f32x4){0.f, 0.f, 0.f, 0.f};
    }

    u32x4 rk[3], rv[3];
    // prologue: K0 -> Ks[0], K1 -> Ks[1] (qtA>=8), V0 -> Vt[0]
#pragma unroll
    for (int it = 0; it < 3; ++it) {
        rk[it] = *(const u32x4*)&qkv[rowb * 2304 + kgo[it]];
        rv[it] = *(const u32x4*)&Vtg[vbase + vgo[it]];
    }
#pragma unroll
    for (int it = 0; it < 3; ++it) {
        *(u32x4*)&KsB[kld[it]] = rk[it];
        *(u32x4*)&VtB[vld[it]] = rv[it];
    }
#pragma unroll
    for (int it = 0; it < 3; ++it)
        rk[it] = *(const u32x4*)&qkv[(rowb + 64) * 2304 + kgo[it]];
#pragma unroll
    for (int it = 0; it < 3; ++it)
        *(u32x4*)&KsB[8192 + kld[it]] = rk[it];
    __syncthreads();

    // QK(0) for both segments
    f32x4 saA[4], sbA[4], saB[4], sbB[4];
    __builtin_amdgcn_s_setprio(1);
#pragma unroll
    for (int j = 0; j < 4; ++j) {
        saA[j] = (f32x4){0.f, 0.f, 0.f, 0.f};
        saB[j] = (f32x4){0.f, 0.f, 0.f, 0.f};
#pragma unroll
        for (int kk = 0; kk < 3; ++kk) {
            short8 kf = *(const short8*)&KsB[(16 * j + lr) * 128 +
                                             (((4 * kk + g) ^ (lr & 7)) << 3)];
            saA[j] = MFMA16(qfA[kk], kf, saA[j]);
            saB[j] = MFMA16(qfB[kk], kf, saB[j]);
        }
    }
    __builtin_amdgcn_s_setprio(0);

    for (int kt = 0; kt <= qtA; ++kt) {
        const int cur = kt & 1;
        // issue-early loads
        if (kt + 2 <= qtA) {
            const size_t nkoff = (rowb + (size_t)(kt + 2) * 64) * 2304;
#pragma unroll
            for (int it = 0; it < 3; ++it)
                rk[it] = *(const u32x4*)&qkv[nkoff + kgo[it]];
        }
        if (kt + 1 <= qtA) {
            const size_t nv = vbase + (size_t)(kt + 1) * 64;
#pragma unroll
            for (int it = 0; it < 3; ++it)
                rv[it] = *(const u32x4*)&Vtg[nv + vgo[it]];
        }

        // pipelined QK(kt+1) from Ks[cur^1]
        if (kt < qtA) {
            const u16* Ksn = KsB + (cur ^ 1) * 8192;
            __builtin_amdgcn_s_setprio(1);
#pragma unroll
            for (int j = 0; j < 4; ++j) {
                sbA[j] = (f32x4){0.f, 0.f, 0.f, 0.f};
#pragma unroll
                for (int kk = 0; kk < 3; ++kk) {
                    short8 kf = *(const short8*)&Ksn[(16 * j + lr) * 128 +
                                                     (((4 * kk + g) ^ (lr & 7)) << 3)];
                    sbA[j] = MFMA16(qfA[kk], kf, sbA[j]);
                }
            }
            if (kt < qtB) {
#pragma unroll
                for (int j = 0; j < 4; ++j) {
                    sbB[j] = (f32x4){0.f, 0.f, 0.f, 0.f};
#pragma unroll
                    for (int kk = 0; kk < 3; ++kk) {
                        short8 kf = *(const short8*)&Ksn[(16 * j + lr) * 128 +
                                                         (((4 * kk + g) ^ (lr & 7)) << 3)];
                        sbB[j] = MFMA16(qfB[kk], kf, sbB[j]);
                    }
                }
            }
            __builtin_amdgcn_s_setprio(0);
        }

        // diagonal masks
        if (kt == qtA) {
#pragma unroll
            for (int j = 0; j < 4; ++j) {
                int lc = 16 * j + lr;
#pragma unroll
                for (int r = 0; r < 4; ++r)
                    if (lc > 16 * wave + 4 * g + r) saA[j][r] = -3e38f;
            }
        }
        if (kt == qtB) {
#pragma unroll
            for (int j = 0; j < 4; ++j) {
                int lc = 16 * j + lr;
#pragma unroll
                for (int r = 0; r < 4; ++r)
                    if (lc > 16 * wave + 4 * g + r) saB[j][r] = -3e38f;
            }
        }

        const u16* Vt = VtB + cur * 6144;

        // ---- segment A: softmax + PV ----
        {
            int cl = 1;
#pragma unroll
            for (int j = 0; j < 4; ++j)
#pragma unroll
                for (int r = 0; r < 4; ++r)
                    cl &= (saA[j][r] <= mA[r] + 11.0f);
            if (!__all(cl)) {
#pragma unroll
                for (int r = 0; r < 4; ++r) {
                    float mx = fmaxf(fmaxf(saA[0][r], saA[1][r]), fmaxf(saA[2][r], saA[3][r]));
#pragma unroll
                    for (int off = 1; off < 16; off <<= 1)
                        mx = fmaxf(mx, __shfl_xor(mx, off, 64));
                    float mn = fmaxf(mA[r], mx);
                    float a = exp2f(mA[r] - mn);
                    mA[r] = mn;
#pragma unroll
                    for (int c = 0; c < 7; ++c) oA[c][r] *= a;
                }
            }
#pragma unroll
            for (int j = 0; j < 4; ++j)
#pragma unroll
                for (int r = 0; r < 4; ++r)
                    PsA[(4 * g + r) * 72 + 16 * j + lr] = f2bf_up(exp2f(saA[j][r] - mA[r]));

            short8 pfr[2];
#pragma unroll
            for (int kk = 0; kk < 2; ++kk)
                pfr[kk] = *(const short8*)&PsA[lr * 72 + 32 * kk + 8 * g];
            __builtin_amdgcn_s_setprio(1);
#pragma unroll
            for (int c = 0; c < 6; ++c)
#pragma unroll
                for (int kk = 0; kk < 2; ++kk) {
                    short8 vf = *(const short8*)&Vt[(16 * c + lr) * 64 +
                                                    (((4 * kk + g) ^ (lr & 7)) << 3)];
                    oA[c] = MFMA16(pfr[kk], vf, oA[c]);
                }
            oA[6] = MFMA16(pfr[0], onesf, oA[6]);
            oA[6] = MFMA16(pfr[1], onesf, oA[6]);
            __builtin_amdgcn_s_setprio(0);
        }

        // ---- segment B: softmax + PV (active while kt <= qtB) ----
        if (kt <= qtB) {
            int cl = 1;
#pragma unroll
            for (int j = 0; j < 4; ++j)
#pragma unroll
                for (int r = 0; r < 4; ++r)
                    cl &= (saB[j][r] <= mB[r] + 11.0f);
            if (!__all(cl)) {
#pragma unroll
                for (int r = 0; r < 4; ++r) {
                    float mx = fmaxf(fmaxf(saB[0][r], saB[1][r]), fmaxf(saB[2][r], saB[3][r]));
#pragma unroll
                    for (int off = 1; off < 16; off <<= 1)
                        mx = fmaxf(mx, __shfl_xor(mx, off, 64));
                    float mn = fmaxf(mB[r], mx);
                    float a = exp2f(mB[r] - mn);
                    mB[r] = mn;
#pragma unroll
                    for (int c = 0; c < 7; ++c) oB[c][r] *= a;
                }
            }
#pragma unroll
            for (int j = 0; j < 4; ++j)
#pragma unroll
                for (int r = 0; r < 4; ++r)
                    PsB[(4 * g + r) * 72 + 16 * j + lr] = f2bf_up(exp2f(saB[j][r] - mB[r]));

            short8 pfr[2];
#pragma unroll
            for (int kk = 0; kk < 2; ++kk)
                pfr[kk] = *(const short8*)&PsB[lr * 72 + 32 * kk + 8 * g];
            __builtin_amdgcn_s_setprio(1);
#pragma unroll
            for (int c = 0; c < 6; ++c)
#pragma unroll
                for (int kk = 0; kk < 2; ++kk) {
                    short8 vf = *(const short8*)&Vt[(16 * c + lr) * 64 +
                                                    (((4 * kk + g) ^ (lr & 7)) << 3)];
                    oB[c] = MFMA16(pfr[kk], vf, oB[c]);
                }
            oB[6] = MFMA16(pfr[0], onesf, oB[6]);
            oB[6] = MFMA16(pfr[1], onesf, oB[6]);
            __builtin_amdgcn_s_setprio(0);
        }

        // write-late staging: K(kt+2) -> Ks[cur], V(kt+1) -> Vt[cur^1]
        if (kt + 2 <= qtA) {
#pragma unroll
            for (int it = 0; it < 3; ++it)
                *(u32x4*)&KsB[cur * 8192 + kld[it]] = rk[it];
        }
        if (kt + 1 <= qtA) {
#pragma unroll
            for (int it = 0; it < 3; ++it)
                *(u32x4*)&VtB[(cur ^ 1) * 6144 + vld[it]] = rv[it];
        }
        __syncthreads();

#pragma unroll
        for (int j = 0; j < 4; ++j) saA[j] = sbA[j];
        if (kt < qtB) {
#pragma unroll
            for (int j = 0; j < 4; ++j) saB[j] = sbB[j];
        }
    }

    // epilogue: both segments write Y into qkv Q region (disjoint q-tiles)
#pragma unroll
    for (int r = 0; r < 4; ++r) {
        int tA = qtA * 64 + 16 * wave + 4 * g + r;
        int tB = qtB * 64 + 16 * wave + 4 * g + r;
        float invA = 1.0f / oA[6][r];
        float invB = 1.0f / oB[6][r];
        size_t roA = (rowb + tA) * 2304 + qcol;
        size_t roB = (rowb + tB) * 2304 + qcol;
#pragma unroll
        for (int c = 0; c < 6; ++c) {
            qkv[roA + 16 * c + lr] = f2bf(oA[c][r] * invA);
            qkv[roB + 16 * c + lr] = f2bf(oB[c][r] * invB);
        }
    }
}

// ---------------- GEMM2: 64x128 tile, 3 blocks/CU, one full residency round ----------------

__global__ __launch_bounds__(256, 3) void k_gemm_out(const u16* __restrict__ A,   // qkv, stride 2304
                                                     const u16* __restrict__ BT,  // [768][768]
                                                     const float* __restrict__ bias,
                                                     float* __restrict__ out) {
    __shared__ __align__(16) u16 lds[2 * 12288];
    const int tid = threadIdx.x;
    int id = blockIdx.x;                        // 768 blocks
    int nid = (id & 7) * 96 + (id >> 3);        // XCD-chunked remap (768 % 8 == 0)
    int by = nid / 6, bx = nid - by * 6;
    const int m0 = by * 64, n0 = bx * 128;

    const u16* Asrc = A + (size_t)m0 * 2304;
    const u16* Bsrc = BT + (size_t)n0 * 768;

    const int lane = tid & 63, wave = tid >> 6;
    const int wr = wave >> 1, wc = wave & 1;
    const int g = lane >> 4, lr = lane & 15;

    f32x4 acc[2][4];
#pragma unroll
    for (int i = 0; i < 2; ++i)
#pragma unroll
        for (int j = 0; j < 4; ++j) acc[i][j] = (f32x4){0.f, 0.f, 0.f, 0.f};

#pragma unroll
    for (int it = 0; it < 2; ++it) {
        int c = tid + it * 256;
        int r = c >> 3, s = c & 7, u = s ^ (r & 7);
        gl_lds16(&Asrc[(size_t)r * 2304 + u * 8], &lds[c * 8]);
    }
#pragma unroll
    for (int it = 0; it < 4; ++it) {
        int c = tid + it * 256;
        int r = c >> 3, s = c & 7, u = s ^ (r & 7);
        gl_lds16(&Bsrc[(size_t)r * 768 + u * 8], &lds[4096 + c * 8]);
    }
    __syncthreads();

    for (int t = 0; t < 12; ++t) {
        const int cur = t & 1;
        if (t < 11) {
            const int k0 = (t + 1) * 64;
            u16* dA = &lds[(cur ^ 1) * 12288];
            u16* dB = dA + 4096;
#pragma unroll
            for (int it = 0; it < 2; ++it) {
                int c = tid + it * 256;
                int r = c >> 3, s = c & 7, u = s ^ (r & 7);
                gl_lds16(&Asrc[(size_t)r * 2304 + k0 + u * 8], &dA[c * 8]);
            }
#pragma unroll
            for (int it = 0; it < 4; ++it) {
                int c = tid + it * 256;
                int r = c >> 3, s = c & 7, u = s ^ (r & 7);
                gl_lds16(&Bsrc[(size_t)r * 768 + k0 + u * 8], &dB[c * 8]);
            }
        }
        const u16* As = &lds[cur * 12288];
        const u16* Bs = As + 4096;
#pragma unroll
        for (int kk = 0; kk < 2; ++kk) {
            const int slot = ((4 * kk + g) ^ (lr & 7)) << 3;
            short8 af[2], bfv[4];
#pragma unroll
            for (int i = 0; i < 2; ++i)
                af[i] = *(const short8*)&As[(32 * wr + 16 * i + lr) * 64 + slot];
#pragma unroll
            for (int j = 0; j < 4; ++j)
                bfv[j] = *(const short8*)&Bs[(64 * wc + 16 * j + lr) * 64 + slot];
#pragma unroll
            for (int i = 0; i < 2; ++i)
#pragma unroll
                for (int j = 0; j < 4; ++j)
                    acc[i][j] = MFMA16(af[i], bfv[j], acc[i][j]);
        }
        if (t < 11) __syncthreads();
    }

#pragma unroll
    for (int i = 0; i < 2; ++i) {
        int row = m0 + 32 * wr + 16 * i + 4 * g;
#pragma unroll
        for (int j = 0; j < 4; ++j) {
            int col = n0 + 64 * wc + 16 * j + lr;
            float bsv = bias[col];
#pragma unroll
            for (int r = 0; r < 4; ++r)
                out[(size_t)(row + r) * 768 + col] = acc[i][j][r] + bsv;
        }
    }
}

// ---------------- launch ----------------

extern "C" void kernel_launch(void* const* d_in, const int* in_sizes, int n_in,
                              void* d_out, int out_size, void* d_ws, size_t ws_size,
                              hipStream_t stream) {
    const float* x      = (const float*)d_in[0];
    const float* w_qkv  = (const float*)d_in[1];
    const float* b_qkv  = (const float*)d_in[2];
    const float* w_proj = (const float*)d_in[3];
    const float* b_proj = (const float*)d_in[4];
    float* out = (float*)d_out;

    u16* xb    = (u16*)d_ws;            // 6291456
    u16* wqkvT = xb + 6291456;          // 1769472
    u16* wpT   = wqkvT + 1769472;       // 589824
    u16* qkv   = wpT + 589824;          // 18874368  [8192][2304]
    u16* Vtg   = qkv + 18874368;        // 6291456   [bh][96][1024]

    k_cvt<<<3648, 256, 0, stream>>>(x, w_qkv, w_proj, xb, wqkvT, wpT);
    k_gemm_qkv<<<768, 256, 0, stream>>>(xb, wqkvT, b_qkv, qkv, Vtg);
    k_attn<<<dim3(8, 64), 256, 0, stream>>>(qkv, Vtg);
    k_gemm_out<<<768, 256, 0, stream>>>(qkv, wpT, b_proj, out);
}

// Round 24
// 103.435 us; speedup vs baseline: 1.3190x; 1.3190x over previous
//
#include <hip/hip_runtime.h>
#include <hip/hip_bf16.h>
#include <stdint.h>

typedef unsigned short u16;
typedef unsigned int u32;
typedef __attribute__((ext_vector_type(8))) short short8;
typedef __attribute__((ext_vector_type(4))) float f32x4;
typedef __attribute__((ext_vector_type(4))) unsigned int u32x4;
typedef __attribute__((ext_vector_type(4))) unsigned short u16x4;

#define MFMA16(a, b, c) __builtin_amdgcn_mfma_f32_16x16x32_bf16((a), (b), (c), 0, 0, 0)

__device__ __forceinline__ u16 f2bf(float f) {
    union { float f; uint32_t u; } v; v.f = f;
    return (u16)((v.u + 0x7FFFu + ((v.u >> 16) & 1u)) >> 16);
}
__device__ __forceinline__ u16 f2bf_up(float f) {  // round-half-up, f >= 0
    union { float f; uint32_t u; } v; v.f = f;
    return (u16)((v.u + 0x8000u) >> 16);
}

// async global -> LDS, 16 bytes per lane (dest must be linear: base + lane*16)
__device__ __forceinline__ void gl_lds16(const u16* g, u16* l) {
    __builtin_amdgcn_global_load_lds(
        (const __attribute__((address_space(1))) u32*)g,
        (__attribute__((address_space(3))) u32*)l,
        16, 0, 0);
}

// ---------------- merged convert kernel (one launch) ----------------
// blocks 0..3071: x f32 -> bf16, 8 elems (32B) per thread. blocks 3072..3647: weight transpose.

__global__ __launch_bounds__(256) void k_cvt(const float* __restrict__ x,
                                             const float* __restrict__ wq,
                                             const float* __restrict__ wp,
                                             u16* __restrict__ xb,
                                             u16* __restrict__ outq,
                                             u16* __restrict__ outp) {
    __shared__ u16 t[64][72];
    if (blockIdx.x < 3072) {
        int i = (blockIdx.x * 256 + threadIdx.x) * 8;
        f32x4 v0 = *(const f32x4*)(x + i);
        f32x4 v1 = *(const f32x4*)(x + i + 4);
        u16x4 o0, o1;
#pragma unroll
        for (int q = 0; q < 4; ++q) { o0[q] = f2bf(v0[q]); o1[q] = f2bf(v1[q]); }
        *(u16x4*)(xb + i) = o0;
        *(u16x4*)(xb + i + 4) = o1;
        return;
    }
    int bid = blockIdx.x - 3072;          // 0..575
    int bx = bid % 48, kb = (bid / 48) * 64;
    const float* in; u16* out; int N, nb;
    if (bx < 36) { in = wq; out = outq; N = 2304; nb = bx * 64; }
    else         { in = wp; out = outp; N = 768;  nb = (bx - 36) * 64; }
    const int tid = threadIdx.x;
    const int r = tid >> 4, c4 = (tid & 15) << 2;
#pragma unroll
    for (int p = 0; p < 4; ++p) {
        int k = r + p * 16;
        f32x4 v = *(const f32x4*)&in[(size_t)(kb + k) * N + nb + c4];
#pragma unroll
        for (int q = 0; q < 4; ++q) t[c4 + q][k] = f2bf(v[q]);
    }
    __syncthreads();
#pragma unroll
    for (int p = 0; p < 4; ++p) {
        int nn = r + p * 16;
        u16x4 o;
#pragma unroll
        for (int q = 0; q < 4; ++q) o[q] = t[nn][c4 + q];
        *(u16x4*)&out[(size_t)(nb + nn) * 768 + kb + c4] = o;
    }
}

// ---------------- GEMM1: persistent-lite 64x128 tiles, grid 768 (r21/r22 proven) ----------------

__global__ __launch_bounds__(256, 3) void k_gemm_qkv(const u16* __restrict__ A,
                                                     const u16* __restrict__ BT,
                                                     const float* __restrict__ bias,
                                                     u16* __restrict__ qkv,
                                                     u16* __restrict__ Vtg) {
    __shared__ __align__(16) u16 lds[2 * 12288];
    const int tid = threadIdx.x;
    int id = blockIdx.x;                        // 768 blocks
    int local = id >> 3, xcd = id & 7;
    int bxg = local >> 4;                       // 0..5
    int by = (xcd << 4) | (local & 15);         // XCD-private 16-row slab
    const int m0 = by * 64;

    const u16* Asrc = A + (size_t)m0 * 768;

    const int lane = tid & 63, wave = tid >> 6;
    const int wr = wave >> 1, wc = wave & 1;
    const int g = lane >> 4, lr = lane & 15;

    int ca[2], ra[2], ua[2], cb[4], rb[4], ub[4];
#pragma unroll
    for (int it = 0; it < 2; ++it) {
        int c = tid + it * 256;
        ca[it] = c; ra[it] = c >> 3; ua[it] = (c & 7) ^ (ra[it] & 7);
    }
#pragma unroll
    for (int it = 0; it < 4; ++it) {
        int c = tid + it * 256;
        cb[it] = c; rb[it] = c >> 3; ub[it] = (c & 7) ^ (rb[it] & 7);
    }

#define STAGE_AB(K0, DST, BSRC) do {                                          \
    u16* dA_ = (DST);                                                         \
    u16* dB_ = (DST) + 4096;                                                  \
    _Pragma("unroll") for (int it = 0; it < 2; ++it)                          \
        gl_lds16(&Asrc[(size_t)ra[it] * 768 + (K0) + ua[it] * 8],             \
                 &dA_[ca[it] * 8]);                                           \
    _Pragma("unroll") for (int it = 0; it < 4; ++it)                          \
        gl_lds16(&(BSRC)[(size_t)rb[it] * 768 + (K0) + ub[it] * 8],           \
                 &dB_[cb[it] * 8]);                                           \
} while (0)

    const float CS = 0.14724449f; // 1/sqrt(96) * log2(e)

    {
        const u16* B0 = BT + (size_t)(bxg * 3) * 128 * 768;
        STAGE_AB(0, lds, B0);
    }
    __syncthreads();

    for (int tile = 0; tile < 3; ++tile) {
        const int bx = bxg * 3 + tile;
        const int n0 = bx * 128;
        const u16* Bcur = BT + (size_t)n0 * 768;

        f32x4 acc[2][4];
#pragma unroll
        for (int i = 0; i < 2; ++i)
#pragma unroll
            for (int j = 0; j < 4; ++j) acc[i][j] = (f32x4){0.f, 0.f, 0.f, 0.f};

        for (int t = 0; t < 12; ++t) {
            const int cur = t & 1;
            if (t < 11) {
                STAGE_AB((t + 1) * 64, &lds[(cur ^ 1) * 12288], Bcur);
            } else if (tile < 2) {
                STAGE_AB(0, &lds[(cur ^ 1) * 12288], Bcur + 98304);
            }
            const u16* As = &lds[cur * 12288];
            const u16* Bs = As + 4096;
#pragma unroll
            for (int kk = 0; kk < 2; ++kk) {
                const int slot = ((4 * kk + g) ^ (lr & 7)) << 3;
                short8 af[2], bfv[4];
#pragma unroll
                for (int i = 0; i < 2; ++i)
                    af[i] = *(const short8*)&As[(32 * wr + 16 * i + lr) * 64 + slot];
#pragma unroll
                for (int j = 0; j < 4; ++j)
                    bfv[j] = *(const short8*)&Bs[(64 * wc + 16 * j + lr) * 64 + slot];
#pragma unroll
                for (int i = 0; i < 2; ++i)
#pragma unroll
                    for (int j = 0; j < 4; ++j)
                        acc[i][j] = MFMA16(af[i], bfv[j], acc[i][j]);
            }
            if (t < 11) __syncthreads();
        }

#pragma unroll
        for (int i = 0; i < 2; ++i) {
            int row = m0 + 32 * wr + 16 * i + 4 * g;
#pragma unroll
            for (int j = 0; j < 4; ++j) {
                int col = n0 + 64 * wc + 16 * j + lr;
                float bsv = bias[col];
                if (col < 1536) {
                    float sc = (col < 768) ? CS : 1.0f;
#pragma unroll
                    for (int r = 0; r < 4; ++r)
                        qkv[(size_t)(row + r) * 2304 + col] = f2bf((acc[i][j][r] + bsv) * sc);
                } else {
                    int jj = col - 1536;
                    int h = jj / 96, d = jj - h * 96;
                    int t2 = row & 1023, bb = row >> 10;
                    int bh = bb * 8 + h;
                    u16x4 vv;
#pragma unroll
                    for (int r = 0; r < 4; ++r) vv[r] = f2bf(acc[i][j][r] + bsv);
                    *(u16x4*)&Vtg[((size_t)bh * 96 + d) * 1024 + t2] = vv;
                }
            }
        }
        if (tile < 2) __syncthreads();
    }
#undef STAGE_AB
}

// ---------------- flash attention (r15/r21 proven: pipelined QK, V 3-slot, 41.7us) ----------------

__global__ __launch_bounds__(256) void k_attn(u16* __restrict__ qkv,
                                              const u16* __restrict__ Vtg) {
    __shared__ __align__(16) u16 sm[16384 + 18432 + 4608];
    u16* KsB = sm;                      // [2][64*128]
    u16* VtB = sm + 16384;              // [3][96*64]
    const int tid = threadIdx.x;
    const int wave = tid >> 6, lane = tid & 63;
    const int g = lane >> 4, lr = lane & 15;
    u16* Ps = sm + 16384 + 18432 + wave * 1152;   // [16][72]

    int id = blockIdx.y * 8 + blockIdx.x;
    int xcd = id & 7, slot = id >> 3;
    int nid = xcd * 64 + slot;
    int z = nid & 7, bh = nid >> 3;
    const int b = bh >> 3, h = bh & 7;

    const size_t rowb = (size_t)b * 1024;
    const int qcol = h * 96;
    const int kcol = 768 + h * 96;
    const size_t vbase = (size_t)bh * 96 * 1024;

    int kld[3], vld[3];
    size_t kgo[3], vgo[3];
#pragma unroll
    for (int it = 0; it < 3; ++it) {
        int c = tid + it * 256;
        int r = c / 12, s = c - r * 12;
        kgo[it] = (size_t)r * 2304 + kcol + s * 8;
        kld[it] = r * 128 + ((s ^ (r & 7)) << 3);
        int vr = c >> 3, vs = c & 7;
        vgo[it] = (size_t)vr * 1024 + vs * 8;
        vld[it] = vr * 64 + ((vs ^ (vr & 7)) << 3);
    }

    const short8 onesf = (short8){0x3F80, 0x3F80, 0x3F80, 0x3F80,
                                  0x3F80, 0x3F80, 0x3F80, 0x3F80};

    for (int seg = 0; seg < 2; ++seg) {
        const int qt = (seg == 0) ? z : 15 - z;
        const int q0 = qt * 64;

        short8 qf[3];
        {
            int qrow = q0 + 16 * wave + lr;
#pragma unroll
            for (int kk = 0; kk < 3; ++kk)
                qf[kk] = *(const short8*)&qkv[(rowb + qrow) * 2304 + qcol + 32 * kk + 8 * g];
        }

        float m_r[4];
        f32x4 o[7]; // o[6] = l (ones-MFMA accumulator)
#pragma unroll
        for (int r = 0; r < 4; ++r) m_r[r] = -3e38f;
#pragma unroll
        for (int c = 0; c < 7; ++c) o[c] = (f32x4){0.f, 0.f, 0.f, 0.f};

        u32x4 rk[3], rv[3];
        // prologue: stage tile 0 (and tile 1 if present)
#pragma unroll
        for (int it = 0; it < 3; ++it) {
            rk[it] = *(const u32x4*)&qkv[rowb * 2304 + kgo[it]];
            rv[it] = *(const u32x4*)&Vtg[vbase + vgo[it]];
        }
#pragma unroll
        for (int it = 0; it < 3; ++it) {
            *(u32x4*)&KsB[kld[it]] = rk[it];
            *(u32x4*)&VtB[vld[it]] = rv[it];
        }
        if (qt > 0) {
#pragma unroll
            for (int it = 0; it < 3; ++it) {
                rk[it] = *(const u32x4*)&qkv[(rowb + 64) * 2304 + kgo[it]];
                rv[it] = *(const u32x4*)&Vtg[vbase + 64 + vgo[it]];
            }
#pragma unroll
            for (int it = 0; it < 3; ++it) {
                *(u32x4*)&KsB[8192 + kld[it]] = rk[it];
                *(u32x4*)&VtB[6144 + vld[it]] = rv[it];
            }
        }
        __syncthreads();

        // QK(0) -> s4a
        f32x4 s4a[4], s4b[4];
        __builtin_amdgcn_s_setprio(1);
#pragma unroll
        for (int j = 0; j < 4; ++j) {
            s4a[j] = (f32x4){0.f, 0.f, 0.f, 0.f};
#pragma unroll
            for (int kk = 0; kk < 3; ++kk) {
                short8 kf = *(const short8*)&KsB[(16 * j + lr) * 128 +
                                                (((4 * kk + g) ^ (lr & 7)) << 3)];
                s4a[j] = MFMA16(qf[kk], kf, s4a[j]);
            }
        }
        __builtin_amdgcn_s_setprio(0);

        int vcur = 0; // V slot of tile kt
        for (int kt = 0; kt <= qt; ++kt) {
            const int cur = kt & 1;
            const int vwr = (vcur == 0) ? 2 : vcur - 1; // slot (kt+2)%3
            const bool pf2 = (kt + 2) <= qt;
            if (pf2) { // issue loads for tile kt+2
                const size_t nkoff = (rowb + (size_t)(kt + 2) * 64) * 2304;
                const size_t nv = vbase + (size_t)(kt + 2) * 64;
#pragma unroll
                for (int it = 0; it < 3; ++it) {
                    rk[it] = *(const u32x4*)&qkv[nkoff + kgo[it]];
                    rv[it] = *(const u32x4*)&Vtg[nv + vgo[it]];
                }
            }

            // QK(kt+1) from Ks[cur^1] (MFMA pipe) -- overlaps softmax(kt) (VALU pipe)
            if (kt < qt) {
                const u16* Ksn = KsB + (cur ^ 1) * 8192;
                __builtin_amdgcn_s_setprio(1);
#pragma unroll
                for (int j = 0; j < 4; ++j) {
                    s4b[j] = (f32x4){0.f, 0.f, 0.f, 0.f};
#pragma unroll
                    for (int kk = 0; kk < 3; ++kk) {
                        short8 kf = *(const short8*)&Ksn[(16 * j + lr) * 128 +
                                                         (((4 * kk + g) ^ (lr & 7)) << 3)];
                        s4b[j] = MFMA16(qf[kk], kf, s4b[j]);
                    }
                }
                __builtin_amdgcn_s_setprio(0);
            }

            if (kt == qt) { // diagonal mask
#pragma unroll
                for (int j = 0; j < 4; ++j) {
                    int lc = 16 * j + lr;
#pragma unroll
                    for (int r = 0; r < 4; ++r) {
                        int lrow = 16 * wave + 4 * g + r;
                        if (lc > lrow) s4a[j][r] = -3e38f;
                    }
                }
            }

            // defer-max online softmax
            int cl = 1;
#pragma unroll
            for (int j = 0; j < 4; ++j)
#pragma unroll
                for (int r = 0; r < 4; ++r)
                    cl &= (s4a[j][r] <= m_r[r] + 11.0f);
            if (!__all(cl)) {
#pragma unroll
                for (int r = 0; r < 4; ++r) {
                    float mx = fmaxf(fmaxf(s4a[0][r], s4a[1][r]), fmaxf(s4a[2][r], s4a[3][r]));
#pragma unroll
                    for (int off = 1; off < 16; off <<= 1)
                        mx = fmaxf(mx, __shfl_xor(mx, off, 64));
                    float mn = fmaxf(m_r[r], mx);
                    float a = exp2f(m_r[r] - mn);
                    m_r[r] = mn;
#pragma unroll
                    for (int c = 0; c < 7; ++c) o[c][r] *= a;
                }
            }
#pragma unroll
            for (int j = 0; j < 4; ++j)
#pragma unroll
                for (int r = 0; r < 4; ++r)
                    Ps[(4 * g + r) * 72 + 16 * j + lr] = f2bf_up(exp2f(s4a[j][r] - m_r[r]));

            // PV(kt) + l (ones fragment); V from slot vcur
            const u16* Vt = VtB + vcur * 6144;
            short8 pfr[2];
#pragma unroll
            for (int kk = 0; kk < 2; ++kk)
                pfr[kk] = *(const short8*)&Ps[lr * 72 + 32 * kk + 8 * g];
            __builtin_amdgcn_s_setprio(1);
#pragma unroll
            for (int c = 0; c < 6; ++c) {
#pragma unroll
                for (int kk = 0; kk < 2; ++kk) {
                    short8 vf = *(const short8*)&Vt[(16 * c + lr) * 64 +
                                                    (((4 * kk + g) ^ (lr & 7)) << 3)];
                    o[c] = MFMA16(pfr[kk], vf, o[c]);
                }
            }
            o[6] = MFMA16(pfr[0], onesf, o[6]);
            o[6] = MFMA16(pfr[1], onesf, o[6]);
            __builtin_amdgcn_s_setprio(0);

            if (pf2) { // write tile kt+2: Ks[cur], Vt[vwr]
#pragma unroll
                for (int it = 0; it < 3; ++it) {
                    *(u32x4*)&KsB[cur * 8192 + kld[it]] = rk[it];
                    *(u32x4*)&VtB[vwr * 6144 + vld[it]] = rv[it];
                }
            }
            __syncthreads();

#pragma unroll
            for (int j = 0; j < 4; ++j) s4a[j] = s4b[j];
            vcur = (vcur == 2) ? 0 : vcur + 1;
        }

        // epilogue: write Y into qkv Q region
#pragma unroll
        for (int r = 0; r < 4; ++r) {
            int t = q0 + 16 * wave + 4 * g + r;
            float inv = 1.0f / o[6][r];
            size_t rowoff = (rowb + t) * 2304 + qcol;
#pragma unroll
            for (int c = 0; c < 6; ++c)
                qkv[rowoff + 16 * c + lr] = f2bf(o[c][r] * inv);
        }
        __syncthreads();
    }
}

// ---------------- GEMM2: 64x128 tile, 3 blocks/CU, one full residency round ----------------

__global__ __launch_bounds__(256, 3) void k_gemm_out(const u16* __restrict__ A,   // qkv, stride 2304
                                                     const u16* __restrict__ BT,  // [768][768]
                                                     const float* __restrict__ bias,
                                                     float* __restrict__ out) {
    __shared__ __align__(16) u16 lds[2 * 12288];
    const int tid = threadIdx.x;
    int id = blockIdx.x;                        // 768 blocks
    int nid = (id & 7) * 96 + (id >> 3);        // XCD-chunked remap (768 % 8 == 0)
    int by = nid / 6, bx = nid - by * 6;
    const int m0 = by * 64, n0 = bx * 128;

    const u16* Asrc = A + (size_t)m0 * 2304;
    const u16* Bsrc = BT + (size_t)n0 * 768;

    const int lane = tid & 63, wave = tid >> 6;
    const int wr = wave >> 1, wc = wave & 1;
    const int g = lane >> 4, lr = lane & 15;

    f32x4 acc[2][4];
#pragma unroll
    for (int i = 0; i < 2; ++i)
#pragma unroll
        for (int j = 0; j < 4; ++j) acc[i][j] = (f32x4){0.f, 0.f, 0.f, 0.f};

#pragma unroll
    for (int it = 0; it < 2; ++it) {
        int c = tid + it * 256;
        int r = c >> 3, s = c & 7, u = s ^ (r & 7);
        gl_lds16(&Asrc[(size_t)r * 2304 + u * 8], &lds[c * 8]);
    }
#pragma unroll
    for (int it = 0; it < 4; ++it) {
        int c = tid + it * 256;
        int r = c >> 3, s = c & 7, u = s ^ (r & 7);
        gl_lds16(&Bsrc[(size_t)r * 768 + u * 8], &lds[4096 + c * 8]);
    }
    __syncthreads();

    for (int t = 0; t < 12; ++t) {
        const int cur = t & 1;
        if (t < 11) {
            const int k0 = (t + 1) * 64;
            u16* dA = &lds[(cur ^ 1) * 12288];
            u16* dB = dA + 4096;
#pragma unroll
            for (int it = 0; it < 2; ++it) {
                int c = tid + it * 256;
                int r = c >> 3, s = c & 7, u = s ^ (r & 7);
                gl_lds16(&Asrc[(size_t)r * 2304 + k0 + u * 8], &dA[c * 8]);
            }
#pragma unroll
            for (int it = 0; it < 4; ++it) {
                int c = tid + it * 256;
                int r = c >> 3, s = c & 7, u = s ^ (r & 7);
                gl_lds16(&Bsrc[(size_t)r * 768 + k0 + u * 8], &dB[c * 8]);
            }
        }
        const u16* As = &lds[cur * 12288];
        const u16* Bs = As + 4096;
#pragma unroll
        for (int kk = 0; kk < 2; ++kk) {
            const int slot = ((4 * kk + g) ^ (lr & 7)) << 3;
            short8 af[2], bfv[4];
#pragma unroll
            for (int i = 0; i < 2; ++i)
                af[i] = *(const short8*)&As[(32 * wr + 16 * i + lr) * 64 + slot];
#pragma unroll
            for (int j = 0; j < 4; ++j)
                bfv[j] = *(const short8*)&Bs[(64 * wc + 16 * j + lr) * 64 + slot];
#pragma unroll
            for (int i = 0; i < 2; ++i)
#pragma unroll
                for (int j = 0; j < 4; ++j)
                    acc[i][j] = MFMA16(af[i], bfv[j], acc[i][j]);
        }
        if (t < 11) __syncthreads();
    }

#pragma unroll
    for (int i = 0; i < 2; ++i) {
        int row = m0 + 32 * wr + 16 * i + 4 * g;
#pragma unroll
        for (int j = 0; j < 4; ++j) {
            int col = n0 + 64 * wc + 16 * j + lr;
            float bsv = bias[col];
#pragma unroll
            for (int r = 0; r < 4; ++r)
                out[(size_t)(row + r) * 768 + col] = acc[i][j][r] + bsv;
        }
    }
}

// ---------------- launch ----------------

extern "C" void kernel_launch(void* const* d_in, const int* in_sizes, int n_in,
                              void* d_out, int out_size, void* d_ws, size_t ws_size,
                              hipStream_t stream) {
    const float* x      = (const float*)d_in[0];
    const float* w_qkv  = (const float*)d_in[1];
    const float* b_qkv  = (const float*)d_in[2];
    const float* w_proj = (const float*)d_in[3];
    const float* b_proj = (const float*)d_in[4];
    float* out = (float*)d_out;

    u16* xb    = (u16*)d_ws;            // 6291456
    u16* wqkvT = xb + 6291456;          // 1769472
    u16* wpT   = wqkvT + 1769472;       // 589824
    u16* qkv   = wpT + 589824;          // 18874368  [8192][2304]
    u16* Vtg   = qkv + 18874368;        // 6291456   [bh][96][1024]

    k_cvt<<<3648, 256, 0, stream>>>(x, w_qkv, w_proj, xb, wqkvT, wpT);
    k_gemm_qkv<<<768, 256, 0, stream>>>(xb, wqkvT, b_qkv, qkv, Vtg);
    k_attn<<<dim3(8, 64), 256, 0, stream>>>(qkv, Vtg);
    k_gemm_out<<<768, 256, 0, stream>>>(qkv, wpT, b_proj, out);
}